// Round 14
// baseline (178.828 us; speedup 1.0000x reference)
//
#include <hip/hip_runtime.h>

// GCN layer, bucket-binned pull aggregation (register accumulate, no float atomics,
// no global int atomics):
//   binning (bucket = row>>6): 3-pass chunked counting sort -> binned[] packed as
//     (row&63)<<26 | col; blkhist layout [chunk][bucket] (coalesced everywhere:
//     histA/scatC row-wise, scanB1 lane-per-bucket serial-over-chunks)
//   degdis: one block per bucket, LDS histogram -> dis + lrp (row scan) for aggregate
//   transform: MFMA bf16 GEMM (x,W -> bf16; 16x16x32, K 48 padded to 64); writes
//     zp rows of 64 bf16 (128 B aligned; features 48..63 zero-padded)
//   aggregate: one block (512 thr) per bucket; LDS counting-sort by row (lrp
//     precomputed); gather with 16-lane x uint2 per edge row -> 4 edge slots/wave,
//     unroll-4 = 16 rows in flight; fused dis*acc+bias+ReLU, float4 stores.
// History: global atomics (R1 983us, R6 66us) and LDS float atomics (R4 499us) are
// dead ends; FMA transform was LDS-issue bound 45us -> MFMA ~9us (R12);
// R7 aggregate was latency-bound at 2.4 TB/s eff -> this round doubles MLP.
// R13 bench was a container-level infra failure (same signature as R10/R11, which
// passed unchanged in R12): identical resubmit after OOB audit found no fault path.

#define NF 48
#define ZLD 32             // zp row stride in uints (128 B aligned)
#define RB 64              // rows per bucket
#define CHUNK 16384        // edges per binning chunk (98 chunks; long scatter runs)
#define SCOL_CAP 2048      // per-bucket LDS col capacity (mean 1024, +32 sigma)

typedef __attribute__((ext_vector_type(8))) short frag_ab;   // 8 bf16
typedef __attribute__((ext_vector_type(4))) float f32x4;

__device__ inline unsigned short f2bf(float f) {
    unsigned u = __float_as_uint(f);
    u = (u + 0x7fffu + ((u >> 16) & 1u)) >> 16;   // RN-even
    return (unsigned short)u;
}

// MFMA transform: zp16[n*64 + f] = bf16( dis[n] * (x[n] @ W^T)[f] ), f=48..63 -> 0
// Block: 256 thr (4 waves), 64 nodes; wave w handles nodes [w*16, w*16+16).
__global__ void transform_kernel(const float* __restrict__ x, const float* __restrict__ W,
                                 const float* __restrict__ dis,
                                 unsigned short* __restrict__ zp16, int N) {
    __shared__ unsigned short Xb[64 * 64];   // 8 KB, row stride 64 (K padded)
    __shared__ unsigned short Wb[48 * 64];   // 6 KB
    const int tid = threadIdx.x;
    const int nb0 = blockIdx.x * 64;

    const float4* x4 = (const float4*)x;
    for (int i = tid; i < 768; i += 256) {
        int r = i / 12, c = i % 12;
        int n = nb0 + r;
        float4 v = (n < N) ? x4[(size_t)n * 12 + c] : make_float4(0.f, 0.f, 0.f, 0.f);
        unsigned short* d = &Xb[r * 64 + c * 4];
        d[0] = f2bf(v.x); d[1] = f2bf(v.y); d[2] = f2bf(v.z); d[3] = f2bf(v.w);
    }
    for (int i = tid; i < 64 * 8; i += 256)
        ((unsigned*)Xb)[(i >> 3) * 32 + 24 + (i & 7)] = 0u;
    const float4* W4 = (const float4*)W;
    for (int i = tid; i < 576; i += 256) {
        int r = i / 12, c = i % 12;
        float4 v = W4[r * 12 + c];
        unsigned short* d = &Wb[r * 64 + c * 4];
        d[0] = f2bf(v.x); d[1] = f2bf(v.y); d[2] = f2bf(v.z); d[3] = f2bf(v.w);
    }
    for (int i = tid; i < 48 * 8; i += 256)
        ((unsigned*)Wb)[(i >> 3) * 32 + 24 + (i & 7)] = 0u;
    __syncthreads();

    const int wv = tid >> 6, lane = tid & 63;
    const int quad = lane >> 4, l16 = lane & 15;
    const int mrow = wv * 16 + l16;

    frag_ab A0 = *(const frag_ab*)&Xb[mrow * 64 + quad * 8];
    frag_ab A1 = *(const frag_ab*)&Xb[mrow * 64 + 32 + quad * 8];
    f32x4 acc[3];
#pragma unroll
    for (int t = 0; t < 3; t++) {
        frag_ab B0 = *(const frag_ab*)&Wb[(t * 16 + l16) * 64 + quad * 8];
        frag_ab B1 = *(const frag_ab*)&Wb[(t * 16 + l16) * 64 + 32 + quad * 8];
        f32x4 z = {0.f, 0.f, 0.f, 0.f};
        z = __builtin_amdgcn_mfma_f32_16x16x32_bf16(A0, B0, z, 0, 0, 0);
        z = __builtin_amdgcn_mfma_f32_16x16x32_bf16(A1, B1, z, 0, 0, 0);
        acc[t] = z;
    }
#pragma unroll
    for (int r = 0; r < 4; r++) {
        int n = nb0 + wv * 16 + quad * 4 + r;
        if (n < N) {
            float dn = dis[n];
            unsigned short* zr = zp16 + (size_t)n * 64;
#pragma unroll
            for (int t = 0; t < 3; t++)
                zr[t * 16 + l16] = f2bf(dn * acc[t][r]);
            zr[48 + l16] = 0;            // feature pad
        }
    }
}

// Pass A: per-chunk bucket histogram; blkhist[chunk][bucket]
__global__ void histA_kernel(const int* __restrict__ row, int* __restrict__ blkhist,
                             int NBUK, int E) {
    extern __shared__ int hist[];       // NBUK ints
    for (int i = threadIdx.x; i < NBUK; i += blockDim.x) hist[i] = 0;
    __syncthreads();
    int b = blockIdx.x;
    int s = b * CHUNK, t = min(E, s + CHUNK);
    int nv = (t - s) >> 2;              // int4 groups
    const int4* r4 = (const int4*)(row + s);
    for (int i = threadIdx.x; i < nv; i += blockDim.x) {
        int4 r = r4[i];
        atomicAdd(&hist[r.x >> 6], 1);
        atomicAdd(&hist[r.y >> 6], 1);
        atomicAdd(&hist[r.z >> 6], 1);
        atomicAdd(&hist[r.w >> 6], 1);
    }
    for (int e = s + nv * 4 + threadIdx.x; e < t; e += blockDim.x)
        atomicAdd(&hist[row[e] >> 6], 1);
    __syncthreads();
    int* dst = blkhist + (size_t)b * NBUK;
    for (int k = threadIdx.x; k < NBUK; k += blockDim.x) dst[k] = hist[k];
}

// Pass B1: lane-per-bucket exclusive scan over chunks, fully coalesced.
__global__ void scanB1_kernel(int* __restrict__ blkhist, int* __restrict__ btotal,
                              int NBUK, int NCH) {
    int k = blockIdx.x * 64 + threadIdx.x;    // bucket id
    if (k >= NBUK) return;
    int carry = 0;
    for (int i = 0; i < NCH; i++) {
        int* p = blkhist + (size_t)i * NBUK + k;
        int v = *p;
        *p = carry;
        carry += v;
    }
    btotal[k] = carry;
}

// Pass B2: single-block exclusive scan of bucket totals -> bbase
__global__ void scanB2_kernel(const int* __restrict__ btotal, int* __restrict__ bbase,
                              int NBUK, int E) {
    __shared__ int wsum[8];
    __shared__ int carry_s;
    if (threadIdx.x == 0) carry_s = 0;
    __syncthreads();
    const int lane = threadIdx.x & 63;
    const int wave = threadIdx.x >> 6;  // blockDim.x == 512
    for (int base = 0; base < NBUK; base += 512) {
        int i = base + threadIdx.x;
        int v = (i < NBUK) ? btotal[i] : 0;
        int incl = v;
        #pragma unroll
        for (int off = 1; off < 64; off <<= 1) {
            int u = __shfl_up(incl, off, 64);
            if (lane >= off) incl += u;
        }
        if (lane == 63) wsum[wave] = incl;
        __syncthreads();
        int woff = 0;
        #pragma unroll
        for (int w = 0; w < 8; w++) if (w < wave) woff += wsum[w];
        if (i < NBUK) bbase[i] = carry_s + woff + (incl - v);
        __syncthreads();
        if (threadIdx.x == 511) carry_s += woff + incl;
        __syncthreads();
    }
    if (threadIdx.x == 0) bbase[NBUK] = E;
}

// Pass C: scatter edges to bucket-grouped binned[], packed (row&63)<<26 | col
__global__ void scatC_kernel(const int* __restrict__ row, const int* __restrict__ col,
                             const int* __restrict__ blkhist, const int* __restrict__ bbase,
                             unsigned* __restrict__ binned, int NBUK, int E) {
    extern __shared__ int cur[];        // NBUK ints
    int b = blockIdx.x;
    const int* boff = blkhist + (size_t)b * NBUK;
    for (int k = threadIdx.x; k < NBUK; k += blockDim.x)
        cur[k] = bbase[k] + boff[k];    // coalesced
    __syncthreads();
    int s = b * CHUNK, t = min(E, s + CHUNK);
    int nv = (t - s) >> 2;
    const int4* r4 = (const int4*)(row + s);
    const int4* c4 = (const int4*)(col + s);
    for (int i = threadIdx.x; i < nv; i += blockDim.x) {
        int4 r = r4[i];
        int4 c = c4[i];
        int p0 = atomicAdd(&cur[r.x >> 6], 1);
        binned[p0] = ((unsigned)(r.x & (RB - 1)) << 26) | (unsigned)c.x;
        int p1 = atomicAdd(&cur[r.y >> 6], 1);
        binned[p1] = ((unsigned)(r.y & (RB - 1)) << 26) | (unsigned)c.y;
        int p2 = atomicAdd(&cur[r.z >> 6], 1);
        binned[p2] = ((unsigned)(r.z & (RB - 1)) << 26) | (unsigned)c.z;
        int p3 = atomicAdd(&cur[r.w >> 6], 1);
        binned[p3] = ((unsigned)(r.w & (RB - 1)) << 26) | (unsigned)c.w;
    }
    for (int e = s + nv * 4 + threadIdx.x; e < t; e += blockDim.x) {
        int r = row[e], c = col[e];
        int pos = atomicAdd(&cur[r >> 6], 1);
        binned[pos] = ((unsigned)(r & (RB - 1)) << 26) | (unsigned)c;
    }
}

// One block per bucket: LDS histogram of row&63 -> dis + per-bucket row scan (lrp_g).
__global__ void degdis_kernel(const int* __restrict__ bbase, const unsigned* __restrict__ binned,
                              float* __restrict__ dis, int* __restrict__ lrp_g, int N) {
    __shared__ int hist[RB];
    const int b = blockIdx.x;
    const int s = bbase[b];
    const int t = bbase[b + 1];
    const int tid = threadIdx.x;
    if (tid < RB) hist[tid] = 0;
    __syncthreads();
    for (int e = s + tid; e < t; e += 512)
        atomicAdd(&hist[binned[e] >> 26], 1);
    __syncthreads();
    if (tid < RB) {
        int v = hist[tid];
        int incl = v;
        #pragma unroll
        for (int off = 1; off < 64; off <<= 1) {
            int u = __shfl_up(incl, off, 64);
            if (tid >= off) incl += u;
        }
        int* lp = lrp_g + (size_t)b * (RB + 1);
        lp[tid] = incl - v;
        if (tid == RB - 1) lp[RB] = incl;
        int n = b * RB + tid;
        if (n < N) dis[n] = (v > 0) ? rsqrtf((float)v) : 0.0f;
    }
}

// One block (512 thr) per bucket: LDS counting sort by row, then 16-lane-per-edge
// uint2 gather: 4 edge slots per wave x unroll 4 = 16 rows in flight.
__global__ __launch_bounds__(512, 8)
void aggregate_kernel(const int* __restrict__ bbase, const unsigned* __restrict__ binned,
                      const int* __restrict__ lrp_g,
                      const uint2* __restrict__ zp2, const float* __restrict__ dis,
                      const float* __restrict__ bias, float* __restrict__ out, int N) {
    __shared__ int scol[SCOL_CAP];
    __shared__ int lrp[RB + 1];
    __shared__ int cur[RB];
    const int b = blockIdx.x;
    const int s = bbase[b];
    const int t = bbase[b + 1];
    const int cnt = t - s;
    const int tid = threadIdx.x;
    if (tid < RB + 1) {
        int v = lrp_g[(size_t)b * (RB + 1) + tid];
        lrp[tid] = v;
        if (tid < RB) cur[tid] = v;
    }
    __syncthreads();
    const bool sorted = (cnt <= SCOL_CAP);
    if (sorted) {
        for (int e = s + tid; e < t; e += 512) {
            unsigned rc = binned[e];
            int pos = atomicAdd(&cur[rc >> 26], 1);
            scol[pos] = (int)(rc & 0x3ffffffu);
        }
    }
    __syncthreads();

    const int lane = tid & 63;
    const int wave = tid >> 6;           // 0..7
    const int slot = lane >> 4;          // 0..3: edge slot
    const int q    = lane & 15;          // quad-feature index; q>=12 reads row pad
    float4 bb = make_float4(0.f, 0.f, 0.f, 0.f);
    if (q < 12) bb = ((const float4*)bias)[q];
    const int rbase = b * RB;
    for (int ri = wave; ri < RB; ri += 8) {
        int r = rbase + ri;
        if (r >= N) break;
        float a0 = 0.f, a1 = 0.f, a2 = 0.f, a3 = 0.f;
        if (sorted) {
            int ks = lrp[ri], ke = lrp[ri + 1];
            int k = ks + slot;
            for (; k + 12 < ke; k += 16) {   // 4 edges per slot: k,k+4,k+8,k+12
                int c0 = scol[k];
                int c1 = scol[k + 4];
                int c2 = scol[k + 8];
                int c3 = scol[k + 12];
                uint2 u0 = zp2[((size_t)c0 << 4) + q];
                uint2 u1 = zp2[((size_t)c1 << 4) + q];
                uint2 u2 = zp2[((size_t)c2 << 4) + q];
                uint2 u3 = zp2[((size_t)c3 << 4) + q];
                a0 += (__uint_as_float(u0.x << 16) + __uint_as_float(u1.x << 16)) +
                      (__uint_as_float(u2.x << 16) + __uint_as_float(u3.x << 16));
                a1 += (__uint_as_float(u0.x & 0xffff0000u) + __uint_as_float(u1.x & 0xffff0000u)) +
                      (__uint_as_float(u2.x & 0xffff0000u) + __uint_as_float(u3.x & 0xffff0000u));
                a2 += (__uint_as_float(u0.y << 16) + __uint_as_float(u1.y << 16)) +
                      (__uint_as_float(u2.y << 16) + __uint_as_float(u3.y << 16));
                a3 += (__uint_as_float(u0.y & 0xffff0000u) + __uint_as_float(u1.y & 0xffff0000u)) +
                      (__uint_as_float(u2.y & 0xffff0000u) + __uint_as_float(u3.y & 0xffff0000u));
            }
            for (; k < ke; k += 4) {
                int c = scol[k];
                uint2 u = zp2[((size_t)c << 4) + q];
                a0 += __uint_as_float(u.x << 16);
                a1 += __uint_as_float(u.x & 0xffff0000u);
                a2 += __uint_as_float(u.y << 16);
                a3 += __uint_as_float(u.y & 0xffff0000u);
            }
        } else {                         // overflow fallback (statistically unreachable)
            for (int e = s; e < t; e++) {
                unsigned rc = binned[e];
                if ((int)(rc >> 26) == ri && slot == 0) {
                    uint2 u = zp2[((size_t)(rc & 0x3ffffffu) << 4) + q];
                    a0 += __uint_as_float(u.x << 16);
                    a1 += __uint_as_float(u.x & 0xffff0000u);
                    a2 += __uint_as_float(u.y << 16);
                    a3 += __uint_as_float(u.y & 0xffff0000u);
                }
            }
        }
        // reduce across the 4 edge slots (lanes differing in bits 4..5)
        a0 += __shfl_xor(a0, 16, 64); a0 += __shfl_xor(a0, 32, 64);
        a1 += __shfl_xor(a1, 16, 64); a1 += __shfl_xor(a1, 32, 64);
        a2 += __shfl_xor(a2, 16, 64); a2 += __shfl_xor(a2, 32, 64);
        a3 += __shfl_xor(a3, 16, 64); a3 += __shfl_xor(a3, 32, 64);
        if (slot == 0 && q < 12) {
            float dr = dis[r];
            float4 o;
            o.x = fmaxf(dr * a0 + bb.x, 0.0f);
            o.y = fmaxf(dr * a1 + bb.y, 0.0f);
            o.z = fmaxf(dr * a2 + bb.z, 0.0f);
            o.w = fmaxf(dr * a3 + bb.w, 0.0f);
            *(float4*)(out + (size_t)r * NF + q * 4) = o;
        }
    }
}

extern "C" void kernel_launch(void* const* d_in, const int* in_sizes, int n_in,
                              void* d_out, int out_size, void* d_ws, size_t ws_size,
                              hipStream_t stream) {
    const float* x    = (const float*)d_in[0];
    const int*   ei   = (const int*)d_in[1];
    const float* W    = (const float*)d_in[2];
    const float* bias = (const float*)d_in[3];
    float* out = (float*)d_out;

    const int N = in_sizes[0] / NF;
    const int E = in_sizes[1] / 2;
    const int* row = ei;                      // edge_index[0]
    const int* col = ei + E;                  // edge_index[1]
    const int NBUK = (N + RB - 1) / RB;       // 1563
    const int NCH  = (E + CHUNK - 1) / CHUNK; // 98

    // workspace layout
    char* ws = (char*)d_ws;
    unsigned* zp      = (unsigned*)ws;       ws += (size_t)N * ZLD * 4;          // 12.8 MB
    unsigned* binned  = (unsigned*)ws;       ws += (size_t)E * 4;                // 6.4 MB
    float*    dis     = (float*)ws;          ws += (size_t)N * 4;
    int*      blkhist = (int*)ws;            ws += (size_t)NCH * NBUK * 4;       // 612 KB
    int*      btotal  = (int*)ws;            ws += (size_t)NBUK * 4;
    int*      bbase   = (int*)ws;            ws += (size_t)(NBUK + 1) * 4;
    int*      lrp_g   = (int*)ws;            ws += (size_t)NBUK * (RB + 1) * 4;  // 406 KB

    histA_kernel<<<NCH, 512, NBUK * 4, stream>>>(row, blkhist, NBUK, E);
    scanB1_kernel<<<(NBUK + 63) / 64, 64, 0, stream>>>(blkhist, btotal, NBUK, NCH);
    scanB2_kernel<<<1, 512, 0, stream>>>(btotal, bbase, NBUK, E);
    scatC_kernel<<<NCH, 512, NBUK * 4, stream>>>(row, col, blkhist, bbase, binned, NBUK, E);
    degdis_kernel<<<NBUK, 512, 0, stream>>>(bbase, binned, dis, lrp_g, N);
    transform_kernel<<<(N + 63) / 64, 256, 0, stream>>>(x, W, dis, (unsigned short*)zp, N);
    aggregate_kernel<<<NBUK, 512, 0, stream>>>(bbase, binned, lrp_g, (const uint2*)zp, dis, bias, out, N);
}